// Round 3
// baseline (614.836 us; speedup 1.0000x reference)
//
#include <hip/hip_runtime.h>

// STFT: N_FFT=1024, HOP=256, WIN=1024, SIG_LEN=2^24, pad=768 each side.
// n_frames=65539 computed frames, n_rows=65542 output rows, half_n=513.
// Circular shift by 512 (zero-phase) == multiply spectrum by (-1)^k.
//
// FULL FP64 PIPELINE: phase branch-cut (atan2 at +/-pi) decisions must match
// the fp64 numpy reference's sign of Yi even at bins where |Yi| ~ 1e-7
// (deep spectral nulls). fp32 FFT error (~1e-6) flips those signs -> 2*pi
// phase errors (rounds 1-2: absmax 6.28125, same bin both rounds). fp64
// error ~1e-15 rel sits far below the dataset's expected min |Yi| ~ 4e-8.

#define SIG_LEN   16777216
#define N_FRAMES  65539
#define N_ROWS    65542
#define HALF_N    513
#define FRAMES_FLOATS (N_FRAMES * HALF_N)   // 33621507
#define MAG_SZ        (N_ROWS   * HALF_N)   // 33623046

// d_ws layout (doubles):
//   [0, 1024)        window (hamming/32)
//   [1024, 1536)     tw: 256 x double2, e^{-2*pi*i*p/512}
//   [1536, 2562)     rtw: 513 x double2, e^{-2*pi*i*k/1024}

__global__ void init_tables(double* __restrict__ ws) {
  int i = blockIdx.x * 256 + threadIdx.x;
  const double PI = 3.14159265358979323846;
  if (i < 1024) {
    ws[i] = (0.54 - 0.46 * cos(2.0 * PI * (double)i / 1023.0)) / 32.0;
  }
  if (i < 256) {
    double a = -2.0 * PI * (double)i / 512.0;
    ws[1024 + 2 * i]     = cos(a);
    ws[1024 + 2 * i + 1] = sin(a);
  }
  if (i < 513) {
    double a = -2.0 * PI * (double)i / 1024.0;
    ws[1536 + 2 * i]     = cos(a);
    ws[1536 + 2 * i + 1] = sin(a);
  }
}

// rows n_frames..n_rows-1 stay zero in the reference; d_out is poisoned, so write them.
__global__ void zero_tail(float* __restrict__ out) {
  int i = blockIdx.x * 256 + threadIdx.x;
  if (i < (MAG_SZ - FRAMES_FLOATS)) {   // 1539 per output
    out[FRAMES_FLOATS + i] = 0.0f;
    out[MAG_SZ + FRAMES_FLOATS + i] = 0.0f;
  }
}

__global__ __launch_bounds__(256) void stft_frame(const float* __restrict__ x,
                                                  const double* __restrict__ ws,
                                                  float* __restrict__ out) {
  __shared__ double  yw[1024];   // windowed frame (fp64)       8 KB
  __shared__ double2 z[512];     // FFT working buffer          8 KB
  __shared__ double2 twl[256];   // 512-point FFT twiddles      4 KB

  const int f = blockIdx.x;
  const int t = threadIdx.x;

  twl[t] = ((const double2*)(ws + 1024))[t];

  // Load + window. Padded signal index = f*HOP + j, x index = that - 768.
  const int base = f * 256 - 768;
#pragma unroll
  for (int jj = 0; jj < 4; ++jj) {
    int j = t + jj * 256;
    int idx = base + j;
    double v = (idx >= 0 && idx < SIG_LEN) ? (double)x[idx] : 0.0;
    yw[j] = v * ws[j];
  }
  __syncthreads();

  // Half-size trick: z[m] = yw[2m] + i*yw[2m+1]; store bit-reversed for DIT.
#pragma unroll
  for (int mm = 0; mm < 2; ++mm) {
    int m = t + mm * 256;
    int r = (int)(__brev((unsigned)m) >> 23);   // 9-bit reverse
    z[r] = make_double2(yw[2 * m], yw[2 * m + 1]);
  }
  __syncthreads();

  // 512-point complex FFT, radix-2 DIT, 9 stages, 256 butterflies/stage.
#pragma unroll
  for (int s = 1; s <= 9; ++s) {
    int half = 1 << (s - 1);
    int p = t & (half - 1);
    int g = t >> (s - 1);
    int i0 = (g << s) | p;
    int i1 = i0 + half;
    double2 w = twl[p << (9 - s)];
    double2 a = z[i0];
    double2 b = z[i1];
    double tr = w.x * b.x - w.y * b.y;
    double ti = w.x * b.y + w.y * b.x;
    z[i0] = make_double2(a.x + tr, a.y + ti);
    z[i1] = make_double2(a.x - tr, a.y - ti);
    __syncthreads();
  }

  // Untwiddle to rfft bins k=0..512, then mag/phase.
  const double2* rtw = (const double2*)(ws + 1536);
  for (int k = t; k < HALF_N; k += 256) {
    double2 Zk = z[k & 511];
    double2 Zm = z[(512 - k) & 511];
    // E = (Zk + conj(Zm))/2 ; O = (Zk - conj(Zm))/(2i) ; Y = E + w*O
    double Er = 0.5 * (Zk.x + Zm.x);
    double Ei = 0.5 * (Zk.y - Zm.y);
    double Dr = Zk.x - Zm.x;
    double Di = Zk.y + Zm.y;
    double Or = 0.5 * Di;
    double Oi = -0.5 * Dr;
    double2 w = rtw[k];
    double Yr = Er + w.x * Or - w.y * Oi;
    double Yi = Ei + w.x * Oi + w.y * Or;
    if ((k & 511) == 0) Yi = 0.0;    // k==0 / k==512: exactly-real bins, imag = +0
    double mag = sqrt(Yr * Yr + Yi * Yi);
    double pr = (k & 1) ? -Yr : Yr;  // (-1)^k from the zero-phase circular shift
    double pi = (k & 1) ? -Yi : Yi;
    double ph = atan2(pi, pr);
    out[f * HALF_N + k] = (float)mag;
    out[MAG_SZ + f * HALF_N + k] = (float)ph;
  }
}

extern "C" void kernel_launch(void* const* d_in, const int* in_sizes, int n_in,
                              void* d_out, int out_size, void* d_ws, size_t ws_size,
                              hipStream_t stream) {
  const float* x = (const float*)d_in[0];
  float* out = (float*)d_out;
  double* ws = (double*)d_ws;

  hipLaunchKernelGGL(init_tables, dim3(4), dim3(256), 0, stream, ws);
  hipLaunchKernelGGL(zero_tail, dim3(7), dim3(256), 0, stream, out);
  hipLaunchKernelGGL(stft_frame, dim3(N_FRAMES), dim3(256), 0, stream, x, ws, out);
}